// Round 4
// baseline (399.078 us; speedup 1.0000x reference)
//
#include <hip/hip_runtime.h>

namespace {

constexpr int Bsz = 8, NC = 10, BC = 80, S = 512, H = 768, G4 = 3072, H2 = 1536;
constexpr int NSP = 8, SCH = 64;
constexpr int NBACK = 128;              // cooperative back-kernel blocks
constexpr int FA_BLK = BC * NSP;        // 640 fusedA blocks
constexpr int XF_BLK = 3072;            // fwd xgate: 1536 row-pairs x 8 groups / 4 waves
constexpr int XB_BLK = 384;             // bwd xgate: 1536 row-pairs / 4 waves
constexpr int FRONT_BLK = FA_BLK + XF_BLK + XB_BLK;  // 4096

__device__ __forceinline__ float sigm(float x){ return 1.0f/(1.0f + __expf(-x)); }
__device__ __forceinline__ float tanh_fast(float x){ return 1.0f - 2.0f/(__expf(2.0f*x) + 1.0f); }

__device__ __forceinline__ float wred(float v){
  #pragma unroll
  for (int m = 32; m; m >>= 1) v += __shfl_xor(v, m, 64);
  return v;
}
__device__ __forceinline__ float dot4(float4 a, float4 b){
  return a.x*b.x + a.y*b.y + a.z*b.z + a.w*b.w;
}
__device__ __forceinline__ void ag_store(float* p, float v){
  __hip_atomic_store(p, v, __ATOMIC_RELAXED, __HIP_MEMORY_SCOPE_AGENT);
}
__device__ __forceinline__ float ag_load(const float* p){
  return __hip_atomic_load(p, __ATOMIC_RELAXED, __HIP_MEMORY_SCOPE_AGENT);
}

// ================= Kernel 1: fusedA || xgate(fwd,bwd) || ctr-zero ===========
__global__ __launch_bounds__(256) void k_front(
    const float* __restrict__ tok, const float* __restrict__ w_tok,
    const float* __restrict__ b_tok, float* __restrict__ win_out,
    float* __restrict__ wpart,
    const float* __restrict__ w_ih_f, const float* __restrict__ b_ih_f, const float* __restrict__ b_hh_f,
    const float* __restrict__ w_ih_b, const float* __restrict__ b_ih_b, const float* __restrict__ b_hh_b,
    float* __restrict__ xg, float* __restrict__ gbwd, unsigned* __restrict__ ctr){
  int blk = blockIdx.x;
  int tid = threadIdx.x, lane = tid & 63, wv = tid >> 6;

  if (blk == 0 && tid < 16) ctr[tid] = 0;   // zero barrier counters for k_back

  if (blk < FA_BLK){
    // ---- fusedA: scores -> windowed -> weighted partial (proven R3 body) ----
    int bc = blk >> 3, ch = blk & 7;
    __shared__ float scr[SCH + 4];
    __shared__ float wsh[SCH];
    int s0 = ch * SCH;
    const float4* w4 = (const float4*)w_tok;
    float4 q0 = w4[lane], q1 = w4[lane + 64], q2 = w4[lane + 128];
    float btok = b_tok[0];
    #pragma unroll
    for (int k = 0; k < 17; k++){
      int r = wv * 17 + k;
      int gs = s0 - 2 + r;
      float sc = 0.f;
      if (gs >= 0 && gs < S){
        const float4* t4 = (const float4*)(tok + ((size_t)bc * S + gs) * H);
        float acc = dot4(t4[lane], q0) + dot4(t4[lane+64], q1) + dot4(t4[lane+128], q2);
        acc = wred(acc);
        sc = sigm(acc + btok);
      }
      if (lane == 0) scr[r] = sc;
    }
    __syncthreads();
    if (tid < SCH){
      float w = (scr[tid] + scr[tid+1] + scr[tid+2] + scr[tid+3] + scr[tid+4]) * 0.2f;
      wsh[tid] = w;
      win_out[(size_t)bc * S + s0 + tid] = w;
    }
    __syncthreads();
    const float* base = tok + ((size_t)bc * S + s0) * H + tid * 3;
    float a0 = 0.f, a1 = 0.f, a2 = 0.f;
    #pragma unroll 4
    for (int s = 0; s < SCH; s++){
      float w = wsh[s];
      const float* p = base + (size_t)s * H;
      a0 += p[0] * w; a1 += p[1] * w; a2 += p[2] * w;
    }
    float* op = wpart + ((size_t)(ch * BC + bc)) * H + tid * 3;
    op[0] = a0; op[1] = a1; op[2] = a2;
    return;
  }

  // ---- xgate ----
  int rp, i0, ni;
  const float* w; const float* bi_; const float* bh_; float* outp;
  bool fwd = (blk < FA_BLK + XF_BLK);
  if (fwd){
    int wg = (blk - FA_BLK) * 4 + wv;   // 0..12287
    rp = wg >> 3;                        // 0..1535
    int grp = wg & 7;
    i0 = grp * 10; ni = 10;
    w = w_ih_f; bi_ = b_ih_f; bh_ = b_hh_f; outp = xg;
  } else {
    rp = (blk - FA_BLK - XF_BLK) * 4 + wv;  // 0..1535
    i0 = 0; ni = Bsz;
    w = w_ih_b; bi_ = b_ih_b; bh_ = b_hh_b; outp = gbwd;
  }
  int r0 = rp * 2, r1 = r0 + 1;
  const float4* wa = (const float4*)(w + (size_t)r0 * H);
  const float4* wb = (const float4*)(w + (size_t)r1 * H);
  float4 u0 = wa[lane], u1 = wa[lane+64], u2 = wa[lane+128];
  float4 v0 = wb[lane], v1 = wb[lane+64], v2 = wb[lane+128];
  float bb0 = bi_[r0] + bh_[r0];
  float bb1 = bi_[r1] + bh_[r1];
  for (int k = 0; k < ni; k++){
    int i = i0 + k;
    size_t bc = fwd ? (size_t)i : ((size_t)i * NC + NC - 1);
    const float4* a4 = (const float4*)(tok + bc * (size_t)S * H);
    float4 a0 = a4[lane], a1 = a4[lane+64], a2 = a4[lane+128];
    float p = dot4(a0,u0) + dot4(a1,u1) + dot4(a2,u2);
    float q = dot4(a0,v0) + dot4(a1,v1) + dot4(a2,v2);
    #pragma unroll
    for (int m = 32; m; m >>= 1){ p += __shfl_xor(p,m,64); q += __shfl_xor(q,m,64); }
    if (lane == 0){
      outp[(size_t)i * G4 + r0] = p + bb0;
      outp[(size_t)i * G4 + r1] = q + bb1;
    }
  }
}

// ================= Kernel 2: cooperative back (custom no-flush barriers) =====
struct BackArgs {
  const float *w_sum, *b_sum, *w_proj, *b_proj;
  const float *w_hh, *xg, *gbwd, *w_cls, *b_cls, *wpart;
  float *wmean, *s1, *summ_out, *hx, *cls_out;
  unsigned *ctr;
};

__global__ __launch_bounds__(256) void k_back(BackArgs A){
  __shared__ float sh[Bsz * H];          // 24 KB staging: wmean / s1 / h
  __shared__ float glob_sh[Bsz * H2];    // 48 KB: block-0 classifier staging
  __shared__ float g_lds[4][6][8];
  __shared__ float c_lds[48];
  int tid = threadIdx.x, lane = tid & 63, wv = tid >> 6, blk = blockIdx.x;
  int gw = blk * 4 + wv;                 // 0..511 global wave id

  auto barrier = [&](int slot){
    __syncthreads();
    if (tid == 0){
      __hip_atomic_fetch_add(&A.ctr[slot], 1u, __ATOMIC_RELEASE, __HIP_MEMORY_SCOPE_AGENT);
      while (__hip_atomic_load(&A.ctr[slot], __ATOMIC_ACQUIRE, __HIP_MEMORY_SCOPE_AGENT) < (unsigned)NBACK)
        __builtin_amdgcn_s_sleep(1);
    }
    __syncthreads();
  };

  // ---- P0: wmean ----
  {
    int idx = blk * 256 + tid;
    if (idx < Bsz * H){
      int b = idx / H, h = idx - b * H;
      float acc = 0.f;
      for (int p = 0; p < NSP; p++)
        #pragma unroll
        for (int c = 0; c < NC; c++)
          acc += A.wpart[((size_t)(p * BC + b * NC + c)) * H + h];
      ag_store(&A.wmean[idx], acc * 0.1f);
    }
  }
  barrier(0);

  // ---- G1: s1 = wmean @ w_sum.T + b_sum ----
  for (int i = tid; i < Bsz * H; i += 256) sh[i] = ag_load(&A.wmean[i]);
  __syncthreads();
  for (int o = gw; o < H; o += 512){
    const float4* w4 = (const float4*)(A.w_sum + (size_t)o * H);
    float4 u0 = w4[lane], u1 = w4[lane+64], u2 = w4[lane+128];
    float bb = A.b_sum[o];
    #pragma unroll
    for (int b = 0; b < Bsz; b++){
      const float4* a4 = (const float4*)(sh + b * H);
      float acc = dot4(a4[lane],u0) + dot4(a4[lane+64],u1) + dot4(a4[lane+128],u2);
      acc = wred(acc);
      if (lane == 0) ag_store(&A.s1[(size_t)b * H + o], acc + bb);
    }
  }
  barrier(1);

  // ---- G2: summ_out = s1 @ w_proj.T + b_proj ----
  __syncthreads();
  for (int i = tid; i < Bsz * H; i += 256) sh[i] = ag_load(&A.s1[i]);
  __syncthreads();
  for (int o = gw; o < H2; o += 512){
    const float4* w4 = (const float4*)(A.w_proj + (size_t)o * H);
    float4 u0 = w4[lane], u1 = w4[lane+64], u2 = w4[lane+128];
    float bb = A.b_proj[o];
    #pragma unroll
    for (int b = 0; b < Bsz; b++){
      const float4* a4 = (const float4*)(sh + b * H);
      float acc = dot4(a4[lane],u0) + dot4(a4[lane+64],u1) + dot4(a4[lane+128],u2);
      acc = wred(acc);
      if (lane == 0) ag_store(&A.summ_out[(size_t)b * H2 + o], acc + bb);
    }
  }

  // ---- LSTM init: h1,c1 from xg[:, t=0, :] (block owns j in [6*blk, 6*blk+6)) ----
  if (tid < 48){
    int jl = tid >> 3, b = tid & 7, j = blk * 6 + jl;
    const float* gp = A.xg + ((size_t)b * NC + 0) * G4 + j;
    float gi = gp[0], gg = gp[2*H], go = gp[3*H];
    float c = sigm(gi) * tanh_fast(gg);
    c_lds[tid] = c;
    float h = sigm(go) * tanh_fast(c);
    ag_store(&A.hx[0 * (Bsz*H) + b * H + j], h);
  }
  barrier(2);

  // ---- LSTM steps t = 1..9: read h_t (buf (t-1)&1) -> gates t+1 -> h_{t+1} (buf t&1)
  for (int t = 1; t <= 9; t++){
    int pr = (t - 1) & 1, pw = t & 1;
    __syncthreads();
    for (int i = tid; i < Bsz * H; i += 256) sh[i] = ag_load(&A.hx[pr * (Bsz*H) + i]);
    __syncthreads();
    #pragma unroll
    for (int jl = 0; jl < 6; jl++){
      int r = wv * H + blk * 6 + jl;      // wave = gate type
      const float4* w4 = (const float4*)(A.w_hh + (size_t)r * H);
      float4 u0 = w4[lane], u1 = w4[lane+64], u2 = w4[lane+128];
      #pragma unroll
      for (int b = 0; b < Bsz; b++){
        const float4* h4 = (const float4*)(sh + b * H);
        float acc = dot4(h4[lane],u0) + dot4(h4[lane+64],u1) + dot4(h4[lane+128],u2);
        acc = wred(acc);
        if (lane == 0) g_lds[wv][jl][b] = acc + A.xg[((size_t)b * NC + t) * G4 + r];
      }
    }
    __syncthreads();
    if (tid < 48){
      int jl = tid >> 3, b = tid & 7, j = blk * 6 + jl;
      float gi = g_lds[0][jl][b], gf = g_lds[1][jl][b];
      float gg = g_lds[2][jl][b], go = g_lds[3][jl][b];
      float c = sigm(gf) * c_lds[tid] + sigm(gi) * tanh_fast(gg);
      c_lds[tid] = c;
      float h = sigm(go) * tanh_fast(c);
      ag_store(&A.hx[pw * (Bsz*H) + b * H + j], h);
    }
    barrier(2 + t);   // slots 3..11
  }

  // ---- fincls on block 0: glob = [h10, hb]; cls = sigmoid((glob+summ) @ w_cls) ----
  if (blk == 0){
    for (int i = tid; i < Bsz * H; i += 256){
      int b = i / H, j = i - b * H;
      glob_sh[b * H2 + j] = ag_load(&A.hx[1 * (Bsz*H) + i]);   // h10 (t=9 wrote buf 1)
      const float* gq = A.gbwd + (size_t)b * G4 + j;
      float cb = sigm(gq[0]) * tanh_fast(gq[2*H]);
      float hb = sigm(gq[3*H]) * tanh_fast(cb);
      glob_sh[b * H2 + H + j] = hb;
    }
    __syncthreads();
    for (int i = tid; i < Bsz * H2; i += 256)
      glob_sh[i] += ag_load(&A.summ_out[i]);
    __syncthreads();
    for (int b = wv; b < Bsz; b += 4){
      const float4* g4 = (const float4*)(glob_sh + (size_t)b * H2);
      const float4* w4 = (const float4*)A.w_cls;
      float acc = 0.f;
      #pragma unroll
      for (int k = 0; k < 6; k++){
        float4 g = g4[lane + k*64], w = w4[lane + k*64];
        acc += g.x*w.x + g.y*w.y + g.z*w.z + g.w*w.w;
      }
      acc = wred(acc);
      if (lane == 0) A.cls_out[b] = sigm(acc + A.b_cls[0]);
    }
  }
}

} // namespace

extern "C" void kernel_launch(void* const* d_in, const int* in_sizes, int n_in,
                              void* d_out, int out_size, void* d_ws, size_t ws_size,
                              hipStream_t stream) {
  const float* tok    = (const float*)d_in[0];
  const float* w_tok  = (const float*)d_in[1];
  const float* b_tok  = (const float*)d_in[2];
  const float* w_sum  = (const float*)d_in[3];
  const float* b_sum  = (const float*)d_in[4];
  const float* w_proj = (const float*)d_in[5];
  const float* b_proj = (const float*)d_in[6];
  const float* w_ih_f = (const float*)d_in[7];
  const float* w_hh_f = (const float*)d_in[8];
  const float* b_ih_f = (const float*)d_in[9];
  const float* b_hh_f = (const float*)d_in[10];
  const float* w_ih_b = (const float*)d_in[11];
  const float* b_ih_b = (const float*)d_in[13];
  const float* b_hh_b = (const float*)d_in[14];
  const float* w_cls  = (const float*)d_in[15];
  const float* b_cls  = (const float*)d_in[16];

  float* out      = (float*)d_out;
  float* cls_out  = out;
  float* win_out  = out + 8;
  float* summ_out = out + 8 + BC * S;

  float* ws     = (float*)d_ws;
  float* wpart  = ws;                         // 491520
  float* wmean  = wpart + (size_t)NSP*BC*H;   // 6144
  float* s1     = wmean + Bsz*H;              // 6144
  float* xg     = s1 + Bsz*H;                 // 245760
  float* gbwd   = xg + (size_t)BC*G4;         // 24576
  float* hx     = gbwd + (size_t)Bsz*G4;      // 12288 (2 x 6144)
  unsigned* ctr = (unsigned*)(hx + 2*Bsz*H);  // 16 uints

  k_front<<<FRONT_BLK, 256, 0, stream>>>(tok, w_tok, b_tok, win_out, wpart,
                                         w_ih_f, b_ih_f, b_hh_f,
                                         w_ih_b, b_ih_b, b_hh_b, xg, gbwd, ctr);

  BackArgs ba;
  ba.w_sum = w_sum; ba.b_sum = b_sum; ba.w_proj = w_proj; ba.b_proj = b_proj;
  ba.w_hh = w_hh_f; ba.xg = xg; ba.gbwd = gbwd; ba.w_cls = w_cls; ba.b_cls = b_cls;
  ba.wpart = wpart; ba.wmean = wmean; ba.s1 = s1; ba.summ_out = summ_out;
  ba.hx = hx; ba.cls_out = cls_out; ba.ctr = ctr;

  void* params[] = { &ba };
  hipLaunchCooperativeKernel(reinterpret_cast<void*>(k_back),
                             dim3(NBACK), dim3(256), params, 0, stream);
}

// Round 5
// 370.521 us; speedup vs baseline: 1.0771x; 1.0771x over previous
//
#include <hip/hip_runtime.h>

namespace {

constexpr int Bsz = 8, NC = 10, BC = 80, S = 512, H = 768, G4 = 3072, H2 = 1536;
constexpr int NSP = 8, SCH = 64;
constexpr int NBACK = 128;              // cooperative back-kernel blocks
constexpr int FA_BLK = BC * NSP;        // 640 fusedA blocks
constexpr int XF_BLK = 3072;            // fwd xgate: 1536 row-pairs x 8 groups / 4 waves
constexpr int XB_BLK = 384;             // bwd xgate: 1536 row-pairs / 4 waves
constexpr int FRONT_BLK = FA_BLK + XF_BLK + XB_BLK;  // 4096

__device__ __forceinline__ float sigm(float x){ return 1.0f/(1.0f + __expf(-x)); }
__device__ __forceinline__ float tanh_fast(float x){ return 1.0f - 2.0f/(__expf(2.0f*x) + 1.0f); }

__device__ __forceinline__ float wred(float v){
  #pragma unroll
  for (int m = 32; m; m >>= 1) v += __shfl_xor(v, m, 64);
  return v;
}
__device__ __forceinline__ float dot4(float4 a, float4 b){
  return a.x*b.x + a.y*b.y + a.z*b.z + a.w*b.w;
}
// device-coherent (agent-scope) data movement, NO ordering fences
__device__ __forceinline__ void ag_store(float* p, float v){
  __hip_atomic_store(p, v, __ATOMIC_RELAXED, __HIP_MEMORY_SCOPE_AGENT);
}
__device__ __forceinline__ float ag_load(const float* p){
  return __hip_atomic_load(p, __ATOMIC_RELAXED, __HIP_MEMORY_SCOPE_AGENT);
}

// ================= Kernel 1: fusedA || xgate(fwd,bwd) || ctr-zero ===========
__global__ __launch_bounds__(256) void k_front(
    const float* __restrict__ tok, const float* __restrict__ w_tok,
    const float* __restrict__ b_tok, float* __restrict__ win_out,
    float* __restrict__ wpart,
    const float* __restrict__ w_ih_f, const float* __restrict__ b_ih_f, const float* __restrict__ b_hh_f,
    const float* __restrict__ w_ih_b, const float* __restrict__ b_ih_b, const float* __restrict__ b_hh_b,
    float* __restrict__ xg, float* __restrict__ gbwd, unsigned* __restrict__ ctr){
  int blk = blockIdx.x;
  int tid = threadIdx.x, lane = tid & 63, wv = tid >> 6;

  if (blk == 0 && tid < 16) ctr[tid] = 0;   // zero barrier counters for k_back

  if (blk < FA_BLK){
    int bc = blk >> 3, ch = blk & 7;
    __shared__ float scr[SCH + 4];
    __shared__ float wsh[SCH];
    int s0 = ch * SCH;
    const float4* w4 = (const float4*)w_tok;
    float4 q0 = w4[lane], q1 = w4[lane + 64], q2 = w4[lane + 128];
    float btok = b_tok[0];
    #pragma unroll
    for (int k = 0; k < 17; k++){
      int r = wv * 17 + k;
      int gs = s0 - 2 + r;
      float sc = 0.f;
      if (gs >= 0 && gs < S){
        const float4* t4 = (const float4*)(tok + ((size_t)bc * S + gs) * H);
        float acc = dot4(t4[lane], q0) + dot4(t4[lane+64], q1) + dot4(t4[lane+128], q2);
        acc = wred(acc);
        sc = sigm(acc + btok);
      }
      if (lane == 0) scr[r] = sc;
    }
    __syncthreads();
    if (tid < SCH){
      float w = (scr[tid] + scr[tid+1] + scr[tid+2] + scr[tid+3] + scr[tid+4]) * 0.2f;
      wsh[tid] = w;
      win_out[(size_t)bc * S + s0 + tid] = w;
    }
    __syncthreads();
    const float* base = tok + ((size_t)bc * S + s0) * H + tid * 3;
    float a0 = 0.f, a1 = 0.f, a2 = 0.f;
    #pragma unroll 4
    for (int s = 0; s < SCH; s++){
      float w = wsh[s];
      const float* p = base + (size_t)s * H;
      a0 += p[0] * w; a1 += p[1] * w; a2 += p[2] * w;
    }
    float* op = wpart + ((size_t)(ch * BC + bc)) * H + tid * 3;
    op[0] = a0; op[1] = a1; op[2] = a2;
    return;
  }

  // ---- xgate ----
  int rp, i0, ni;
  const float* w; const float* bi_; const float* bh_; float* outp;
  bool fwd = (blk < FA_BLK + XF_BLK);
  if (fwd){
    int wg = (blk - FA_BLK) * 4 + wv;   // 0..12287
    rp = wg >> 3;                        // 0..1535
    int grp = wg & 7;
    i0 = grp * 10; ni = 10;
    w = w_ih_f; bi_ = b_ih_f; bh_ = b_hh_f; outp = xg;
  } else {
    rp = (blk - FA_BLK - XF_BLK) * 4 + wv;  // 0..1535
    i0 = 0; ni = Bsz;
    w = w_ih_b; bi_ = b_ih_b; bh_ = b_hh_b; outp = gbwd;
  }
  int r0 = rp * 2, r1 = r0 + 1;
  const float4* wa = (const float4*)(w + (size_t)r0 * H);
  const float4* wb = (const float4*)(w + (size_t)r1 * H);
  float4 u0 = wa[lane], u1 = wa[lane+64], u2 = wa[lane+128];
  float4 v0 = wb[lane], v1 = wb[lane+64], v2 = wb[lane+128];
  float bb0 = bi_[r0] + bh_[r0];
  float bb1 = bi_[r1] + bh_[r1];
  for (int k = 0; k < ni; k++){
    int i = i0 + k;
    size_t bc = fwd ? (size_t)i : ((size_t)i * NC + NC - 1);
    const float4* a4 = (const float4*)(tok + bc * (size_t)S * H);
    float4 a0 = a4[lane], a1 = a4[lane+64], a2 = a4[lane+128];
    float p = dot4(a0,u0) + dot4(a1,u1) + dot4(a2,u2);
    float q = dot4(a0,v0) + dot4(a1,v1) + dot4(a2,v2);
    #pragma unroll
    for (int m = 32; m; m >>= 1){ p += __shfl_xor(p,m,64); q += __shfl_xor(q,m,64); }
    if (lane == 0){
      outp[(size_t)i * G4 + r0] = p + bb0;
      outp[(size_t)i * G4 + r1] = q + bb1;
    }
  }
}

// ================= Kernel 2: cooperative back, RELAXED (flush-free) barriers =
struct BackArgs {
  const float *w_sum, *b_sum, *w_proj, *b_proj;
  const float *w_hh, *xg, *gbwd, *w_cls, *b_cls, *wpart;
  float *wmean, *s1, *summ_out, *hx, *cls_out;
  unsigned *ctr;
};

__global__ __launch_bounds__(256) void k_back(BackArgs A){
  __shared__ float sh_a[Bsz * H];        // 24 KB: wmean / s1 staging
  __shared__ float sh_h[Bsz * H];        // 24 KB: h staging
  __shared__ float glob_sh[Bsz * H2];    // 48 KB: block-0 classifier staging
  __shared__ float g_lds[4][6][8];
  __shared__ float c_lds[48];
  int tid = threadIdx.x, lane = tid & 63, wv = tid >> 6, blk = blockIdx.x;
  int gw = blk * 4 + wv;                 // 0..511 global wave id

  // flush-free grid barrier: drain own stores (wave-local), relaxed arrive,
  // relaxed coherent spin. NO acquire/release -> no buffer_inv / wbl2 storms.
  auto gbar = [&](int slot){
    asm volatile("s_waitcnt vmcnt(0)" ::: "memory");
    __syncthreads();
    if (tid == 0){
      __hip_atomic_fetch_add(&A.ctr[slot], 1u, __ATOMIC_RELAXED, __HIP_MEMORY_SCOPE_AGENT);
      while (__hip_atomic_load(&A.ctr[slot], __ATOMIC_RELAXED, __HIP_MEMORY_SCOPE_AGENT) < (unsigned)NBACK)
        __builtin_amdgcn_s_sleep(2);
    }
    __syncthreads();
  };

  // combined phase: optional small-GEMM + LSTM step t (reads hx[pr], writes hx[pw])
  auto phase = [&](int t, int gemm){
    int pr = (t - 1) & 1, pw = t & 1;
    if (gemm == 1) for (int i = tid; i < Bsz * H; i += 256) sh_a[i] = ag_load(&A.wmean[i]);
    if (gemm == 2) for (int i = tid; i < Bsz * H; i += 256) sh_a[i] = ag_load(&A.s1[i]);
    for (int i = tid; i < Bsz * H; i += 256) sh_h[i] = ag_load(&A.hx[pr * (Bsz*H) + i]);
    __syncthreads();
    if (gemm == 1){
      for (int o = gw; o < H; o += 512){
        const float4* w4 = (const float4*)(A.w_sum + (size_t)o * H);
        float4 u0 = w4[lane], u1 = w4[lane+64], u2 = w4[lane+128];
        float bb = A.b_sum[o];
        #pragma unroll
        for (int b = 0; b < Bsz; b++){
          const float4* a4 = (const float4*)(sh_a + b * H);
          float acc = dot4(a4[lane],u0) + dot4(a4[lane+64],u1) + dot4(a4[lane+128],u2);
          acc = wred(acc);
          if (lane == 0) ag_store(&A.s1[(size_t)b * H + o], acc + bb);
        }
      }
    } else if (gemm == 2){
      for (int o = gw; o < H2; o += 512){
        const float4* w4 = (const float4*)(A.w_proj + (size_t)o * H);
        float4 u0 = w4[lane], u1 = w4[lane+64], u2 = w4[lane+128];
        float bb = A.b_proj[o];
        #pragma unroll
        for (int b = 0; b < Bsz; b++){
          const float4* a4 = (const float4*)(sh_a + b * H);
          float acc = dot4(a4[lane],u0) + dot4(a4[lane+64],u1) + dot4(a4[lane+128],u2);
          acc = wred(acc);
          if (lane == 0) ag_store(&A.summ_out[(size_t)b * H2 + o], acc + bb);
        }
      }
    }
    // gates for step t: wave = gate type, block owns j in [6*blk, 6*blk+6)
    #pragma unroll
    for (int jl = 0; jl < 6; jl++){
      int r = wv * H + blk * 6 + jl;
      const float4* w4 = (const float4*)(A.w_hh + (size_t)r * H);
      float4 u0 = w4[lane], u1 = w4[lane+64], u2 = w4[lane+128];
      #pragma unroll
      for (int b = 0; b < Bsz; b++){
        const float4* h4 = (const float4*)(sh_h + b * H);
        float acc = dot4(h4[lane],u0) + dot4(h4[lane+64],u1) + dot4(h4[lane+128],u2);
        acc = wred(acc);
        if (lane == 0) g_lds[wv][jl][b] = acc + A.xg[((size_t)b * NC + t) * G4 + r];
      }
    }
    __syncthreads();
    if (tid < 48){
      int jl = tid >> 3, b = tid & 7, j = blk * 6 + jl;
      float gi = g_lds[0][jl][b], gf = g_lds[1][jl][b];
      float gg = g_lds[2][jl][b], go = g_lds[3][jl][b];
      float c = sigm(gf) * c_lds[tid] + sigm(gi) * tanh_fast(gg);
      c_lds[tid] = c;
      float h = sigm(go) * tanh_fast(c);
      ag_store(&A.hx[pw * (Bsz*H) + b * H + j], h);
    }
  };

  // ---- Phase A: wmean || LSTM init (h1,c1 from xg[:,t=0,:]) ----
  {
    int idx = blk * 256 + tid;
    if (idx < Bsz * H){
      int b = idx / H, h = idx - b * H;
      float acc = 0.f;
      for (int p = 0; p < NSP; p++)
        #pragma unroll
        for (int c = 0; c < NC; c++)
          acc += A.wpart[((size_t)(p * BC + b * NC + c)) * H + h];
      ag_store(&A.wmean[idx], acc * 0.1f);
    }
    if (tid < 48){
      int jl = tid >> 3, b = tid & 7, j = blk * 6 + jl;
      const float* gp = A.xg + ((size_t)b * NC + 0) * G4 + j;
      float c = sigm(gp[0]) * tanh_fast(gp[2*H]);
      c_lds[tid] = c;
      float h = sigm(gp[3*H]) * tanh_fast(c);
      ag_store(&A.hx[0 * (Bsz*H) + b * H + j], h);
    }
  }
  gbar(0);
  phase(1, 1); gbar(1);        // s1-GEMM || step1
  phase(2, 2); gbar(2);        // summ-GEMM || step2
  for (int t = 3; t <= 9; t++){ phase(t, 0); gbar(t); }

  // ---- fincls on block 0 ----
  if (blk == 0){
    for (int i = tid; i < Bsz * H; i += 256){
      int b = i / H, j = i - b * H;
      glob_sh[b * H2 + j] = ag_load(&A.hx[1 * (Bsz*H) + i]);   // h10 (t=9 wrote buf 1)
      const float* gq = A.gbwd + (size_t)b * G4 + j;
      float cb = sigm(gq[0]) * tanh_fast(gq[2*H]);
      float hb = sigm(gq[3*H]) * tanh_fast(cb);
      glob_sh[b * H2 + H + j] = hb;
    }
    __syncthreads();
    for (int i = tid; i < Bsz * H2; i += 256)
      glob_sh[i] += ag_load(&A.summ_out[i]);
    __syncthreads();
    for (int b = wv; b < Bsz; b += 4){
      const float4* g4 = (const float4*)(glob_sh + (size_t)b * H2);
      const float4* w4 = (const float4*)A.w_cls;
      float acc = 0.f;
      #pragma unroll
      for (int k = 0; k < 6; k++){
        float4 g = g4[lane + k*64], w = w4[lane + k*64];
        acc += g.x*w.x + g.y*w.y + g.z*w.z + g.w*w.w;
      }
      acc = wred(acc);
      if (lane == 0) A.cls_out[b] = sigm(acc + A.b_cls[0]);
    }
  }
}

} // namespace

extern "C" void kernel_launch(void* const* d_in, const int* in_sizes, int n_in,
                              void* d_out, int out_size, void* d_ws, size_t ws_size,
                              hipStream_t stream) {
  const float* tok    = (const float*)d_in[0];
  const float* w_tok  = (const float*)d_in[1];
  const float* b_tok  = (const float*)d_in[2];
  const float* w_sum  = (const float*)d_in[3];
  const float* b_sum  = (const float*)d_in[4];
  const float* w_proj = (const float*)d_in[5];
  const float* b_proj = (const float*)d_in[6];
  const float* w_ih_f = (const float*)d_in[7];
  const float* w_hh_f = (const float*)d_in[8];
  const float* b_ih_f = (const float*)d_in[9];
  const float* b_hh_f = (const float*)d_in[10];
  const float* w_ih_b = (const float*)d_in[11];
  const float* b_ih_b = (const float*)d_in[13];
  const float* b_hh_b = (const float*)d_in[14];
  const float* w_cls  = (const float*)d_in[15];
  const float* b_cls  = (const float*)d_in[16];

  float* out      = (float*)d_out;
  float* cls_out  = out;
  float* win_out  = out + 8;
  float* summ_out = out + 8 + BC * S;

  float* ws     = (float*)d_ws;
  float* wpart  = ws;                         // 491520
  float* wmean  = wpart + (size_t)NSP*BC*H;   // 6144
  float* s1     = wmean + Bsz*H;              // 6144
  float* xg     = s1 + Bsz*H;                 // 245760
  float* gbwd   = xg + (size_t)BC*G4;         // 24576
  float* hx     = gbwd + (size_t)Bsz*G4;      // 12288 (2 x 6144)
  unsigned* ctr = (unsigned*)(hx + 2*Bsz*H);  // 16 uints

  k_front<<<FRONT_BLK, 256, 0, stream>>>(tok, w_tok, b_tok, win_out, wpart,
                                         w_ih_f, b_ih_f, b_hh_f,
                                         w_ih_b, b_ih_b, b_hh_b, xg, gbwd, ctr);

  BackArgs ba;
  ba.w_sum = w_sum; ba.b_sum = b_sum; ba.w_proj = w_proj; ba.b_proj = b_proj;
  ba.w_hh = w_hh_f; ba.xg = xg; ba.gbwd = gbwd; ba.w_cls = w_cls; ba.b_cls = b_cls;
  ba.wpart = wpart; ba.wmean = wmean; ba.s1 = s1; ba.summ_out = summ_out;
  ba.hx = hx; ba.cls_out = cls_out; ba.ctr = ctr;

  void* params[] = { &ba };
  hipLaunchCooperativeKernel(reinterpret_cast<void*>(k_back),
                             dim3(NBACK), dim3(256), params, 0, stream);
}

// Round 6
// 225.117 us; speedup vs baseline: 1.7728x; 1.6459x over previous
//
#include <hip/hip_runtime.h>

namespace {

constexpr int Bsz = 8, NC = 10, BC = 80, S = 512, H = 768, G4 = 3072, H2 = 1536;
constexpr int FA_CH = 32, FA_ROWS = 16, FA_STG = 20;   // fusedA: 32 chunks x 16 rows + 4 halo
constexpr int FA_BLK = BC * FA_CH;                     // 2560
constexpr int XF_BLK = 960, XB_BLK = 96;               // xgate fwd/bwd blocks
constexpr int FRONT_BLK = FA_BLK + XF_BLK + XB_BLK;    // 3616
constexpr int NBACK = 96;                              // cooperative back blocks
constexpr int HP = 772;                                // padded LDS row stride (dwords)

typedef float f32x4 __attribute__((ext_vector_type(4)));

__device__ __forceinline__ float sigm(float x){ return 1.0f/(1.0f + __expf(-x)); }
__device__ __forceinline__ float tanh_fast(float x){ return 1.0f - 2.0f/(__expf(2.0f*x) + 1.0f); }
__device__ __forceinline__ float vdot(f32x4 a, f32x4 b){ f32x4 m = a*b; return m.x+m.y+m.z+m.w; }
__device__ __forceinline__ float wred(float v){
  #pragma unroll
  for (int m = 32; m; m >>= 1) v += __shfl_xor(v, m, 64);
  return v;
}

// ---- coherent (cross-XCD, MALL-level) loads/stores: sc0 sc1 ----
__device__ __forceinline__ void coh_load6(f32x4 (&d)[6],
    const f32x4* p0, const f32x4* p1, const f32x4* p2,
    const f32x4* p3, const f32x4* p4, const f32x4* p5){
  asm volatile(
    "global_load_dwordx4 %0, %6, off sc0 sc1\n\t"
    "global_load_dwordx4 %1, %7, off sc0 sc1\n\t"
    "global_load_dwordx4 %2, %8, off sc0 sc1\n\t"
    "global_load_dwordx4 %3, %9, off sc0 sc1\n\t"
    "global_load_dwordx4 %4, %10, off sc0 sc1\n\t"
    "global_load_dwordx4 %5, %11, off sc0 sc1\n\t"
    "s_waitcnt vmcnt(0)"
    : "=&v"(d[0]), "=&v"(d[1]), "=&v"(d[2]), "=&v"(d[3]), "=&v"(d[4]), "=&v"(d[5])
    : "v"(p0), "v"(p1), "v"(p2), "v"(p3), "v"(p4), "v"(p5)
    : "memory");
}
__device__ __forceinline__ void coh_store1(float* p, float v){
  asm volatile("global_store_dword %0, %1, off sc0 sc1" :: "v"(p), "v"(v) : "memory");
}

// ================= Kernel 1: fusedA (single-pass) || xgate (no-wred) =========
__global__ __launch_bounds__(256) void k_front(
    const float* __restrict__ tok, const float* __restrict__ w_tok,
    const float* __restrict__ b_tok, float* __restrict__ win_out,
    float* __restrict__ wpart,
    const float* __restrict__ w_ih_f, const float* __restrict__ b_ih_f, const float* __restrict__ b_hh_f,
    const float* __restrict__ w_ih_b, const float* __restrict__ b_ih_b, const float* __restrict__ b_hh_b,
    float* __restrict__ xg, float* __restrict__ gbwd, unsigned* __restrict__ ctr){
  __shared__ float smemF[FA_STG * HP];   // 61760 B
  __shared__ float scr[FA_STG];
  __shared__ float wsh[FA_ROWS];
  int blk = blockIdx.x, tid = threadIdx.x;

  if (blk == 0 && tid < 16) ctr[tid] = 0;

  if (blk < FA_BLK){
    // ---------- fusedA: one HBM pass ----------
    int bc = blk >> 5, ch = blk & 31;
    int s0 = ch * FA_ROWS;
    #pragma unroll
    for (int i = 0; i < 15; i++){                 // stage 20 rows (halo +-2)
      int f = i * 256 + tid;                      // 0..3839
      int row = f / 192, c4 = f % 192;
      int gs = s0 - 2 + row;
      if (gs >= 0 && gs < S)
        *(f32x4*)&smemF[row * HP + c4 * 4] =
          *(const f32x4*)&tok[((size_t)bc * S + gs) * H + c4 * 4];
    }
    __syncthreads();
    if (tid < 80){                                // scores: 20 rows x 4 quarters
      int r = tid >> 2, q = tid & 3;
      int gs = s0 - 2 + r;
      const f32x4* wq = (const f32x4*)w_tok + q * 48;
      float acc = 0.f;
      #pragma unroll 8
      for (int k = 0; k < 48; k++)
        acc += vdot(*(const f32x4*)&smemF[r * HP + (q * 48 + k) * 4], wq[k]);
      acc += __shfl_xor(acc, 1, 64);
      acc += __shfl_xor(acc, 2, 64);
      if (q == 0) scr[r] = (gs >= 0 && gs < S) ? sigm(acc + b_tok[0]) : 0.f;
    }
    __syncthreads();
    if (tid < FA_ROWS){
      float w = (scr[tid] + scr[tid+1] + scr[tid+2] + scr[tid+3] + scr[tid+4]) * 0.2f;
      wsh[tid] = w;
      win_out[(size_t)bc * S + s0 + tid] = w;
    }
    __syncthreads();
    if (tid < 192){                               // weighted partial
      f32x4 acc = {0.f, 0.f, 0.f, 0.f};
      #pragma unroll
      for (int i = 0; i < FA_ROWS; i++){
        float w = wsh[i];
        f32x4 a = *(const f32x4*)&smemF[(i + 2) * HP + tid * 4];
        acc += a * w;
      }
      *(f32x4*)&wpart[((size_t)ch * BC + bc) * H + tid * 4] = acc;
    }
    return;
  }

  // ---------- xgate: thread-per-(row,batch), LDS-staged tok rows ----------
  int xb = blk - FA_BLK;
  bool fwd = (xb < XF_BLK);
  int rblk, base_bc = 0;
  const float *w, *bi, *bh; float* outp;
  if (fwd){ rblk = xb / 10; base_bc = (xb % 10) * 8; w = w_ih_f; bi = b_ih_f; bh = b_hh_f; outp = xg; }
  else    { rblk = xb - XF_BLK;                      w = w_ih_b; bi = b_ih_b; bh = b_hh_b; outp = gbwd; }
  #pragma unroll
  for (int i = 0; i < 6; i++){                    // stage 8 tok rows
    int f = i * 256 + tid;
    int bl = f / 192, c4 = f % 192;
    size_t bc = fwd ? (size_t)(base_bc + bl) : ((size_t)bl * NC + NC - 1);
    *(f32x4*)&smemF[bl * HP + c4 * 4] = *(const f32x4*)&tok[bc * (size_t)S * H + c4 * 4];
  }
  __syncthreads();
  {
    int bl = tid & 7, rl = tid >> 3;
    int r = rblk * 32 + rl;
    const f32x4* wr = (const f32x4*)(w + (size_t)r * H);
    float acc = 0.f;
    #pragma unroll 8
    for (int k = 0; k < 192; k++)
      acc += vdot(*(const f32x4*)&smemF[bl * HP + k * 4], wr[k]);
    int ob = fwd ? (base_bc + bl) : bl;
    outp[(size_t)ob * G4 + r] = acc + bi[r] + bh[r];
  }
}

// ================= Kernel 2: cooperative back ================================
struct BackArgs {
  const float *w_sum, *b_sum, *w_proj, *b_proj;
  const float *w_hh, *xg, *gbwd, *w_cls, *b_cls, *wpart;
  float *wmean, *s1, *summ_out, *hx, *cls_out;
  unsigned *ctr;
};

__global__ __launch_bounds__(256) void k_back(BackArgs A){
  __shared__ float smem[12672];                  // h_sh | a_sh | c_sh | g_sh (50.7 KB)
  float* h_sh = smem;                            // [8][772]
  float* a_sh = smem + 6176;                     // [8][772]
  float* c_sh = smem + 12352;                    // [64]
  float* g_sh = smem + 12416;                    // [8jl][4g][8b]
  int tid = threadIdx.x, blkx = blockIdx.x;

  auto gbar = [&](int slot){
    asm volatile("s_waitcnt vmcnt(0)" ::: "memory");
    __syncthreads();
    if (tid == 0){
      __hip_atomic_fetch_add(&A.ctr[slot], 1u, __ATOMIC_RELAXED, __HIP_MEMORY_SCOPE_AGENT);
      while (__hip_atomic_load(&A.ctr[slot], __ATOMIC_RELAXED, __HIP_MEMORY_SCOPE_AGENT) < (unsigned)NBACK)
        __builtin_amdgcn_s_sleep(1);
    }
    __syncthreads();
  };

  auto stage6 = [&](float* dst, const float* src){     // 6144 floats -> padded LDS
    const f32x4* s4 = (const f32x4*)src;
    f32x4 d[6];
    coh_load6(d, s4 + tid, s4 + 256 + tid, s4 + 512 + tid,
                 s4 + 768 + tid, s4 + 1024 + tid, s4 + 1280 + tid);
    #pragma unroll
    for (int i = 0; i < 6; i++){
      int f = i * 256 + tid;
      int b = f / 192, j4 = f % 192;
      *(f32x4*)&dst[b * HP + j4 * 4] = d[i];
    }
  };

  // step t: g = xg[:,t,:] + h_t @ W^T ; combine -> h_{t+1}, c_{t+1}
  auto do_step = [&](int t){
    int jl = tid >> 5, g = (tid >> 3) & 3, b = tid & 7;
    int j = blkx * 8 + jl;
    int r = g * H + j;
    const f32x4* wr = (const f32x4*)(A.w_hh + (size_t)r * H);
    float acc = 0.f;
    #pragma unroll 8
    for (int k = 0; k < 192; k++)
      acc += vdot(*(const f32x4*)&h_sh[b * HP + k * 4], wr[k]);
    g_sh[jl * 32 + g * 8 + b] = acc + A.xg[((size_t)b * NC + t) * G4 + r];
    __syncthreads();
    if (tid < 64){
      int jl2 = tid >> 3, b2 = tid & 7;
      float gi = g_sh[jl2*32 + b2],      gf = g_sh[jl2*32 + 8 + b2];
      float gg = g_sh[jl2*32 + 16 + b2], go = g_sh[jl2*32 + 24 + b2];
      float c = sigm(gf) * c_sh[tid] + sigm(gi) * tanh_fast(gg);
      c_sh[tid] = c;
      coh_store1(&A.hx[(t & 1) * (Bsz*H) + b2 * H + blkx * 8 + jl2],
                 sigm(go) * tanh_fast(c));
    }
  };

  // ---- P0: wmean + LSTM init (h1,c1 from xg[:,0,:]) ----
  if (tid < 64){
    int idx = blkx * 64 + tid;
    int b = idx / H, hh = idx % H;
    float acc = 0.f;
    for (int p = 0; p < FA_CH; p++)
      #pragma unroll
      for (int c = 0; c < NC; c++)
        acc += A.wpart[((size_t)p * BC + b * NC + c) * H + hh];
    coh_store1(&A.wmean[idx], acc * 0.1f);
    int jl = tid >> 3, b2 = tid & 7, j = blkx * 8 + jl;
    const float* gp = A.xg + (size_t)(b2 * NC) * G4;
    float c = sigm(gp[j]) * tanh_fast(gp[2*H + j]);
    c_sh[tid] = c;
    coh_store1(&A.hx[b2 * H + j], sigm(gp[3*H + j]) * tanh_fast(c));
  }
  gbar(0);

  // ---- P1: s1 = wmean @ w_sum.T  ||  step1 ----
  stage6(a_sh, A.wmean);
  stage6(h_sh, A.hx);            // h1 (buf 0)
  __syncthreads();
  {
    int out = tid >> 2, q = tid & 3;
    int ol = out >> 3, b = out & 7;
    int o = blkx * 8 + ol;
    const f32x4* wq = (const f32x4*)(A.w_sum + (size_t)o * H) + q * 48;
    float acc = 0.f;
    #pragma unroll 8
    for (int k = 0; k < 48; k++)
      acc += vdot(*(const f32x4*)&a_sh[b * HP + (q * 48 + k) * 4], wq[k]);
    acc += __shfl_xor(acc, 1, 64);
    acc += __shfl_xor(acc, 2, 64);
    if (q == 0) coh_store1(&A.s1[(size_t)b * H + o], acc + A.b_sum[o]);
  }
  do_step(1);
  gbar(1);

  // ---- P2: summ = s1 @ w_proj.T  ||  step2 ----
  stage6(a_sh, A.s1);
  stage6(h_sh, A.hx + (Bsz*H));  // h2 (buf 1)
  __syncthreads();
  {
    int out = tid >> 1, hf = tid & 1;
    int ol = out >> 3, b = out & 7;
    int o = blkx * 16 + ol;
    const f32x4* wq = (const f32x4*)(A.w_proj + (size_t)o * H) + hf * 96;
    float acc = 0.f;
    #pragma unroll 8
    for (int k = 0; k < 96; k++)
      acc += vdot(*(const f32x4*)&a_sh[b * HP + (hf * 96 + k) * 4], wq[k]);
    acc += __shfl_xor(acc, 1, 64);
    if (hf == 0) coh_store1(&A.summ_out[(size_t)b * H2 + o], acc + A.b_proj[o]);
  }
  do_step(2);
  gbar(2);

  // ---- steps 3..9 ----
  for (int t = 3; t <= 9; t++){
    stage6(h_sh, A.hx + ((t - 1) & 1) * (Bsz*H));
    __syncthreads();
    do_step(t);
    gbar(t);
  }

  // ---- fincls on block 0: comb = [h10|hb] + summ ; cls ----
  if (blkx == 0){
    float* comb = smem;                          // 12288 floats
    {
      const f32x4* s4 = (const f32x4*)(A.hx + Bsz*H);   // h10 in buf 1
      f32x4 d[6];
      coh_load6(d, s4 + tid, s4 + 256 + tid, s4 + 512 + tid,
                   s4 + 768 + tid, s4 + 1024 + tid, s4 + 1280 + tid);
      #pragma unroll
      for (int i = 0; i < 6; i++){
        int f = i * 256 + tid;
        int b = f / 192, j4 = f % 192;
        *(f32x4*)&comb[b * H2 + j4 * 4] = d[i];
      }
    }
    #pragma unroll
    for (int u = 0; u < 6; u++){                 // hb from gbwd (regular loads)
      int f = u * 256 + tid;
      int b = f / 192, j4 = f % 192;
      f32x4 gi = *(const f32x4*)&A.gbwd[(size_t)b * G4 + j4 * 4];
      f32x4 gg = *(const f32x4*)&A.gbwd[(size_t)b * G4 + 2*H + j4 * 4];
      f32x4 go = *(const f32x4*)&A.gbwd[(size_t)b * G4 + 3*H + j4 * 4];
      f32x4 hb;
      hb.x = sigm(go.x) * tanh_fast(sigm(gi.x) * tanh_fast(gg.x));
      hb.y = sigm(go.y) * tanh_fast(sigm(gi.y) * tanh_fast(gg.y));
      hb.z = sigm(go.z) * tanh_fast(sigm(gi.z) * tanh_fast(gg.z));
      hb.w = sigm(go.w) * tanh_fast(sigm(gi.w) * tanh_fast(gg.w));
      *(f32x4*)&comb[b * H2 + H + j4 * 4] = hb;
    }
    __syncthreads();
    {
      const f32x4* s4 = (const f32x4*)A.summ_out;
      f32x4 d[6];
      coh_load6(d, s4 + tid, s4 + 256 + tid, s4 + 512 + tid,
                   s4 + 768 + tid, s4 + 1024 + tid, s4 + 1280 + tid);
      #pragma unroll
      for (int i = 0; i < 6; i++){ int f = i * 256 + tid; *(f32x4*)&comb[f * 4] += d[i]; }
      coh_load6(d, s4 + 1536 + tid, s4 + 1792 + tid, s4 + 2048 + tid,
                   s4 + 2304 + tid, s4 + 2560 + tid, s4 + 2816 + tid);
      #pragma unroll
      for (int i = 0; i < 6; i++){ int f = 1536 + i * 256 + tid; *(f32x4*)&comb[f * 4] += d[i]; }
    }
    __syncthreads();
    int wv = tid >> 6, lane = tid & 63;
    for (int b = wv; b < Bsz; b += 4){
      const f32x4* c4 = (const f32x4*)&comb[b * H2];
      const f32x4* wc = (const f32x4*)A.w_cls;
      float acc = 0.f;
      #pragma unroll
      for (int k = 0; k < 6; k++)
        acc += vdot(c4[lane + 64*k], wc[lane + 64*k]);
      acc = wred(acc);
      if (lane == 0) A.cls_out[b] = sigm(acc + A.b_cls[0]);
    }
  }
}

} // namespace

extern "C" void kernel_launch(void* const* d_in, const int* in_sizes, int n_in,
                              void* d_out, int out_size, void* d_ws, size_t ws_size,
                              hipStream_t stream) {
  const float* tok    = (const float*)d_in[0];
  const float* w_tok  = (const float*)d_in[1];
  const float* b_tok  = (const float*)d_in[2];
  const float* w_sum  = (const float*)d_in[3];
  const float* b_sum  = (const float*)d_in[4];
  const float* w_proj = (const float*)d_in[5];
  const float* b_proj = (const float*)d_in[6];
  const float* w_ih_f = (const float*)d_in[7];
  const float* w_hh_f = (const float*)d_in[8];
  const float* b_ih_f = (const float*)d_in[9];
  const float* b_hh_f = (const float*)d_in[10];
  const float* w_ih_b = (const float*)d_in[11];
  const float* b_ih_b = (const float*)d_in[13];
  const float* b_hh_b = (const float*)d_in[14];
  const float* w_cls  = (const float*)d_in[15];
  const float* b_cls  = (const float*)d_in[16];

  float* out      = (float*)d_out;
  float* cls_out  = out;
  float* win_out  = out + 8;
  float* summ_out = out + 8 + BC * S;

  float* ws     = (float*)d_ws;
  float* wpart  = ws;                              // 32*80*768 = 1,966,080
  float* wmean  = wpart + (size_t)FA_CH * BC * H;  // 6144
  float* s1     = wmean + Bsz * H;                 // 6144
  float* xg     = s1 + Bsz * H;                    // 245760
  float* gbwd   = xg + (size_t)BC * G4;            // 24576
  float* hx     = gbwd + (size_t)Bsz * G4;         // 12288 (2 bufs)
  unsigned* ctr = (unsigned*)(hx + 2 * Bsz * H);   // 16

  k_front<<<FRONT_BLK, 256, 0, stream>>>(tok, w_tok, b_tok, win_out, wpart,
                                         w_ih_f, b_ih_f, b_hh_f,
                                         w_ih_b, b_ih_b, b_hh_b, xg, gbwd, ctr);

  BackArgs ba;
  ba.w_sum = w_sum; ba.b_sum = b_sum; ba.w_proj = w_proj; ba.b_proj = b_proj;
  ba.w_hh = w_hh_f; ba.xg = xg; ba.gbwd = gbwd; ba.w_cls = w_cls; ba.b_cls = b_cls;
  ba.wpart = wpart; ba.wmean = wmean; ba.s1 = s1; ba.summ_out = summ_out;
  ba.hx = hx; ba.cls_out = cls_out; ba.ctr = ctr;

  void* params[] = { &ba };
  hipLaunchCooperativeKernel(reinterpret_cast<void*>(k_back),
                             dim3(NBACK), dim3(256), params, 0, stream);
}